// Round 1
// 915.799 us; speedup vs baseline: 1.2985x; 1.2985x over previous
//
#include <hip/hip_runtime.h>

typedef unsigned int uint;
typedef unsigned short u16;
typedef unsigned long long u64;
typedef float v4f __attribute__((ext_vector_type(4)));

#define N_NODES 8192
#define IN_F    512
#define OUT_F   64
#define CHEADS  2
#define ROWS    (N_NODES * CHEADS)   // 16384
#define ROW_LEN N_NODES              // 8192
#define BLK     256
#define PER_TH  (ROW_LEN / BLK)      // 32 elements per thread
#define VCHUNKS (PER_TH / 4)         // 8 x float4 per thread
#define CAND_CAP 2048
#define SEL_CAP  64

__device__ __forceinline__ float bits_to_float(uint u) {
    union { uint u; float f; } cv; cv.u = u; return cv.f;
}
__device__ __forceinline__ uint float_to_bits(float f) {
    union { uint u; float f; } cv; cv.f = f; return cv.u;
}
// order-preserving fp32 bits -> uint transform
__device__ __forceinline__ uint sortable32(uint u) {
    return u ^ ((u & 0x80000000u) ? 0xFFFFFFFFu : 0x80000000u);
}
__device__ __forceinline__ uint unsortable32(uint s) {
    return (s & 0x80000000u) ? (s ^ 0x80000000u) : ~s;
}
__device__ __forceinline__ float key_to_val(uint key) {
    return bits_to_float(unsortable32(key));
}

// Defensive decode of the scalar k (int32 / int64 / bf16 / fp32 all -> 32)
__device__ __forceinline__ int decode_k(const void* p) {
    int ki = *(const int*)p;
    if (ki >= 1 && ki <= ROW_LEN) return ki;
    {
        uint b = *(const u16*)p;
        float f = bits_to_float(b << 16);
        int kf = (int)f;
        if (f == (float)kf && kf >= 1 && kf <= ROW_LEN) return kf;
    }
    {
        float g = *(const float*)p;
        int kg = (int)g;
        if (g == (float)kg && kg >= 1 && kg <= ROW_LEN) return kg;
    }
    return 32;
}

// descending bitonic sort of 64 values, one per lane, via shfl_xor.
// final order: lane 0 = max ... lane 63 = min.
__device__ __forceinline__ uint bitonic_desc_u32(uint v, const int lane) {
    #pragma unroll
    for (int size = 2; size <= 64; size <<= 1) {
        #pragma unroll
        for (int stride = size >> 1; stride > 0; stride >>= 1) {
            const uint pv = (uint)__shfl_xor((int)v, stride, 64);
            const bool takeMax = (((lane & stride) != 0) == ((lane & size) != 0));
            v = takeMax ? (v >= pv ? v : pv) : (v <= pv ? v : pv);
        }
    }
    return v;
}

__device__ __forceinline__ u64 bitonic_desc_u64(u64 v, const int lane) {
    #pragma unroll
    for (int size = 2; size <= 64; size <<= 1) {
        #pragma unroll
        for (int stride = size >> 1; stride > 0; stride >>= 1) {
            const u64 pv = __shfl_xor(v, stride, 64);
            const bool takeMax = (((lane & stride) != 0) == ((lane & size) != 0));
            v = takeMax ? (v >= pv ? v : pv) : (v <= pv ? v : pv);
        }
    }
    return v;
}

// -------- kernel 1: h = x @ W^T (fp32), LDS-tiled, coalesced --------
// block computes a 32-row x 64-col tile; K staged in chunks of 128.
// thread (r = tid&15, fb = 4*(tid>>4)) computes rows {r, r+16}, cols {fb..fb+3}.
#define HM    32
#define HK    128
#define XS_LD 132   // pad 128 -> 132 floats: LDS reads land <=2-way (free)

__global__ __launch_bounds__(256) void h_kernel(
    const float* __restrict__ x, const float* __restrict__ W, float* __restrict__ hbuf)
{
    __shared__ float x_s[HM * XS_LD];      // 16.9 KB
    __shared__ float w_s[OUT_F * XS_LD];   // 33.8 KB
    const int tid = threadIdx.x;
    const int n0  = blockIdx.x * HM;
    const int r   = tid & 15;
    const int fb  = (tid >> 4) << 2;

    float a00 = 0.f, a01 = 0.f, a02 = 0.f, a03 = 0.f;
    float a10 = 0.f, a11 = 0.f, a12 = 0.f, a13 = 0.f;

    for (int c = 0; c < IN_F; c += HK) {
        // stage x chunk: 32 rows x 128 cols = 1024 float4, 4 per thread
        #pragma unroll
        for (int j = 0; j < 4; ++j) {
            const int id  = tid + 256 * j;
            const int row = id >> 5;
            const int c4  = id & 31;
            float4 v = *reinterpret_cast<const float4*>(x + (size_t)(n0 + row) * IN_F + c + 4 * c4);
            *reinterpret_cast<float4*>(&x_s[row * XS_LD + 4 * c4]) = v;
        }
        // stage W chunk: 64 rows x 128 cols = 2048 float4, 8 per thread
        #pragma unroll
        for (int j = 0; j < 8; ++j) {
            const int id  = tid + 256 * j;
            const int row = id >> 5;
            const int c4  = id & 31;
            float4 v = *reinterpret_cast<const float4*>(W + (size_t)row * IN_F + c + 4 * c4);
            *reinterpret_cast<float4*>(&w_s[row * XS_LD + 4 * c4]) = v;
        }
        __syncthreads();

        #pragma unroll 4
        for (int k4 = 0; k4 < HK / 4; ++k4) {
            const float4 x0 = *reinterpret_cast<const float4*>(&x_s[r * XS_LD + 4 * k4]);
            const float4 x1 = *reinterpret_cast<const float4*>(&x_s[(r + 16) * XS_LD + 4 * k4]);
            const float4 w0 = *reinterpret_cast<const float4*>(&w_s[(fb + 0) * XS_LD + 4 * k4]);
            const float4 w1 = *reinterpret_cast<const float4*>(&w_s[(fb + 1) * XS_LD + 4 * k4]);
            const float4 w2 = *reinterpret_cast<const float4*>(&w_s[(fb + 2) * XS_LD + 4 * k4]);
            const float4 w3 = *reinterpret_cast<const float4*>(&w_s[(fb + 3) * XS_LD + 4 * k4]);
            a00 = fmaf(x0.x, w0.x, a00); a00 = fmaf(x0.y, w0.y, a00); a00 = fmaf(x0.z, w0.z, a00); a00 = fmaf(x0.w, w0.w, a00);
            a01 = fmaf(x0.x, w1.x, a01); a01 = fmaf(x0.y, w1.y, a01); a01 = fmaf(x0.z, w1.z, a01); a01 = fmaf(x0.w, w1.w, a01);
            a02 = fmaf(x0.x, w2.x, a02); a02 = fmaf(x0.y, w2.y, a02); a02 = fmaf(x0.z, w2.z, a02); a02 = fmaf(x0.w, w2.w, a02);
            a03 = fmaf(x0.x, w3.x, a03); a03 = fmaf(x0.y, w3.y, a03); a03 = fmaf(x0.z, w3.z, a03); a03 = fmaf(x0.w, w3.w, a03);
            a10 = fmaf(x1.x, w0.x, a10); a10 = fmaf(x1.y, w0.y, a10); a10 = fmaf(x1.z, w0.z, a10); a10 = fmaf(x1.w, w0.w, a10);
            a11 = fmaf(x1.x, w1.x, a11); a11 = fmaf(x1.y, w1.y, a11); a11 = fmaf(x1.z, w1.z, a11); a11 = fmaf(x1.w, w1.w, a11);
            a12 = fmaf(x1.x, w2.x, a12); a12 = fmaf(x1.y, w2.y, a12); a12 = fmaf(x1.z, w2.z, a12); a12 = fmaf(x1.w, w2.w, a12);
            a13 = fmaf(x1.x, w3.x, a13); a13 = fmaf(x1.y, w3.y, a13); a13 = fmaf(x1.z, w3.z, a13); a13 = fmaf(x1.w, w3.w, a13);
        }
        __syncthreads();
    }

    float4 o0; o0.x = a00; o0.y = a01; o0.z = a02; o0.w = a03;
    float4 o1; o1.x = a10; o1.y = a11; o1.z = a12; o1.w = a13;
    *reinterpret_cast<float4*>(hbuf + (size_t)(n0 + r) * OUT_F + fb)      = o0;
    *reinterpret_cast<float4*>(hbuf + (size_t)(n0 + r + 16) * OUT_F + fb) = o1;
}

// -------- kernel 2: per-row exact top-k + softmax + spmm + dense att write --------
__global__ __launch_bounds__(BLK) void topk_kernel(
    const float* __restrict__ attn,
    const float* __restrict__ hbuf,
    const void* __restrict__ kptr,
    float* __restrict__ outp,      // [N][C*OUT_F]
    float* __restrict__ att_out)   // [ROWS][ROW_LEN]
{
    __shared__ uint  s_lmax[BLK];
    __shared__ uint  s_ck[CAND_CAP];     // candidate sortable keys
    __shared__ u16   s_cidx[CAND_CAP];   // candidate indices
    __shared__ int   s_sel_idx[SEL_CAP];
    __shared__ float s_sel_w[SEL_CAP];
    __shared__ float s_lsum[4];
    __shared__ uint  s_bc[4];            // [0]=pivot p, [1]=max key, [2]=V32, [3]=Tlow
    __shared__ int   s_cnt[2];
    __shared__ float s_l;
    __shared__ int   s_scnt;

    const int tid = threadIdx.x;
    const int row = blockIdx.x;
    int k = decode_k(kptr);              // 32
    if (k > SEL_CAP) k = SEL_CAP;

    if (tid == 0) { s_cnt[0] = 0; s_cnt[1] = 0; }

    const float* rowp = attn    + (size_t)row * ROW_LEN;
    float*       orow = att_out + (size_t)row * ROW_LEN;

    // phase 0: load row (fp32) into registers as sortable keys; per-thread max
    uint lk[PER_TH];
    uint lmax = 0;
    #pragma unroll
    for (int c = 0; c < VCHUNKS; ++c) {
        const int base = (c * BLK + tid) * 4;
        float4 v = *reinterpret_cast<const float4*>(rowp + base);
        const uint k0 = sortable32(float_to_bits(v.x));
        const uint k1 = sortable32(float_to_bits(v.y));
        const uint k2 = sortable32(float_to_bits(v.z));
        const uint k3 = sortable32(float_to_bits(v.w));
        lk[c * 4 + 0] = k0; lk[c * 4 + 1] = k1;
        lk[c * 4 + 2] = k2; lk[c * 4 + 3] = k3;
        lmax = max(max(max(lmax, k0), max(k1, k2)), k3);
    }
    s_lmax[tid] = lmax;
    __syncthreads();                                           // A

    // phase 1: wave 0 sorts the 64 combined (max-of-4) maxima -> pivot + row max.
    //          waves 1-3 (previously idle here) zero-fill the dense att row with
    //          non-temporal stores; selected entries are scattered over it later.
    if (tid < 64) {
        uint cmb = max(max(s_lmax[tid], s_lmax[tid + 64]),
                       max(s_lmax[tid + 128], s_lmax[tid + 192]));
        cmb = bitonic_desc_u32(cmb, tid);
        const uint pk = (uint)__shfl((int)cmb, k - 1, 64);     // k-th largest group max
        if (tid == 0) { s_bc[0] = pk; s_bc[1] = cmb; }         // lane0 = global max
    } else {
        const int t = tid - 64;                                // 0..191
        v4f z = {0.f, 0.f, 0.f, 0.f};
        for (int i = t; i < ROW_LEN / 4; i += 192)
            __builtin_nontemporal_store(z, reinterpret_cast<v4f*>(orow) + i);
    }
    __syncthreads();                                           // B
    const uint  p = s_bc[0];
    const float m = key_to_val(s_bc[1]);                       // row max value

    // phase 2: compact candidates (keys >= p); expected ~44
    #pragma unroll
    for (int e = 0; e < PER_TH; ++e) {
        if (lk[e] >= p) {
            int pos = atomicAdd(&s_cnt[0], 1);
            if (pos < CAND_CAP) {
                const int c = e >> 2, j = e & 3;
                s_ck[pos]   = lk[e];
                s_cidx[pos] = (u16)((c * BLK + tid) * 4 + j);
            }
        }
    }
    __syncthreads();                                           // C

    int cnt = s_cnt[0];
    if (cnt > CAND_CAP) cnt = CAND_CAP;
    const bool fast = (cnt <= 64);                             // block-uniform

    if (fast) {
        // phase 3 fast: one bitonic sort gives exact top-k with lax.top_k
        // tie-break (value desc, index asc), weights, and the denominator.
        if (tid < 64) {
            u64 v = 0ull;
            if (tid < cnt)
                v = ((u64)s_ck[tid] << 13) | (u64)(0x1FFFu ^ (uint)s_cidx[tid]);
            v = bitonic_desc_u64(v, tid);
            const uint key = (uint)(v >> 13);
            const int  idx = (int)(0x1FFFu ^ (uint)(v & 0x1FFFull));
            const float w  = (tid < k) ? __expf(key_to_val(key) - m) : 0.f;
            float lsum = w;
            #pragma unroll
            for (int off = 1; off < 64; off <<= 1) lsum += __shfl_xor(lsum, off, 64);
            if (tid < k) { s_sel_idx[tid] = idx; s_sel_w[tid] = w; }
            if (tid == 0) { s_l = lsum; s_scnt = k; }
        }
        __syncthreads();                                       // D
    } else {
        // fallback (P(cnt>64) ~ 1e-7/row): exact binary-search selection, as before
        if (tid < 64) {
            // V32 = largest V with count(key >= V) >= k
            uint lo = p, hi = 0xFFFFFFFFu;
            while (lo < hi) {
                const uint d = hi - lo;
                const uint mid = lo + (d >> 1) + (d & 1u);
                int c = 0;
                for (int j = tid; j < cnt; j += 64) c += (s_ck[j] >= mid) ? 1 : 0;
                #pragma unroll
                for (int off = 1; off < 64; off <<= 1) c += __shfl_xor(c, off, 64);
                if (c >= k) lo = mid; else hi = mid - 1;
            }
            const uint V32 = lo;
            int g = 0;
            for (int j = tid; j < cnt; j += 64) g += (s_ck[j] > V32) ? 1 : 0;
            #pragma unroll
            for (int off = 1; off < 64; off <<= 1) g += __shfl_xor(g, off, 64);
            const int e_need = k - g;
            uint tlo = 0u, thi = 0x1FFFu;
            while (tlo < thi) {
                const uint d = thi - tlo;
                const uint mid = tlo + (d >> 1) + (d & 1u);
                int c = 0;
                for (int j = tid; j < cnt; j += 64)
                    c += (s_ck[j] == V32 && (0x1FFFu ^ (uint)s_cidx[j]) >= mid) ? 1 : 0;
                #pragma unroll
                for (int off = 1; off < 64; off <<= 1) c += __shfl_xor(c, off, 64);
                if (c >= e_need) tlo = mid; else thi = mid - 1;
            }
            if (tid == 0) { s_bc[2] = V32; s_bc[3] = tlo; }
        }
        __syncthreads();                                       // D
        const uint V32  = s_bc[2];
        const uint Tlow = s_bc[3];
        float lsum = 0.f;
        #pragma unroll
        for (int e = 0; e < PER_TH; ++e) {
            const int idx = ((e >> 2) * BLK + tid) * 4 + (e & 3);
            const bool sel = (lk[e] > V32) || (lk[e] == V32 && (0x1FFFu ^ (uint)idx) >= Tlow);
            if (sel) {
                const float w = __expf(key_to_val(lk[e]) - m);
                lsum += w;
                int pos = atomicAdd(&s_cnt[1], 1);
                if (pos < SEL_CAP) { s_sel_idx[pos] = idx; s_sel_w[pos] = w; }
            }
        }
        #pragma unroll
        for (int off = 1; off < 64; off <<= 1) lsum += __shfl_xor(lsum, off, 64);
        if ((tid & 63) == 0) s_lsum[tid >> 6] = lsum;
        __syncthreads();                                       // E
        if (tid == 0) {
            s_l = s_lsum[0] + s_lsum[1] + s_lsum[2] + s_lsum[3];
            int sc = s_cnt[1]; if (sc > SEL_CAP) sc = SEL_CAP;
            s_scnt = sc;
        }
        __syncthreads();                                       // F
    }

    const float l     = s_l;
    const float inv_l = (l > 0.f) ? (1.0f / l) : 0.f;
    const int   scnt  = s_scnt;

    // scatter normalized weights over the zeroed att row (wave 1; safe: barriers
    // above drained the zero-fill stores via vmcnt(0))
    if (tid >= 64 && tid < 64 + scnt) {
        const int j = tid - 64;
        orow[s_sel_idx[j]] = s_sel_w[j] * inv_l;
    }

    // h_prime row (sparse gather) -> out, interleaved layout (wave 0)
    const int n  = row & (N_NODES - 1);
    const int ch = row >> 13;
    if (tid < OUT_F) {
        float acc = 0.f;
        for (int j = 0; j < scnt; ++j)
            acc += s_sel_w[j] * hbuf[(size_t)s_sel_idx[j] * OUT_F + tid];
        outp[(size_t)n * (CHEADS * OUT_F) + ch * OUT_F + tid] = acc * inv_l;
    }
}

extern "C" void kernel_launch(void* const* d_in, const int* in_sizes, int n_in,
                              void* d_out, int out_size, void* d_ws, size_t ws_size,
                              hipStream_t stream) {
    const float* x    = (const float*)d_in[0];
    const float* W    = (const float*)d_in[1];
    const float* attn = (const float*)d_in[2];
    const void*  kptr = (const void*)d_in[3];

    float* hbuf = (float*)d_ws;                                   // 8192*64 fp32 = 2 MB
    float* outp = (float*)d_out;                                  // [8192][128]
    float* att_out = outp + (size_t)N_NODES * (CHEADS * OUT_F);   // [16384][8192]

    hipLaunchKernelGGL(h_kernel,    dim3(N_NODES / HM), dim3(BLK), 0, stream, x, W, hbuf);
    hipLaunchKernelGGL(topk_kernel, dim3(ROWS),         dim3(BLK), 0, stream, attn, hbuf, kptr, outp, att_out);
}

// Round 2
// 895.291 us; speedup vs baseline: 1.3283x; 1.0229x over previous
//
#include <hip/hip_runtime.h>

typedef unsigned int uint;
typedef unsigned short u16;
typedef unsigned long long u64;
typedef float v4f __attribute__((ext_vector_type(4)));

#define N_NODES 8192
#define IN_F    512
#define OUT_F   64
#define CHEADS  2
#define ROWS    (N_NODES * CHEADS)   // 16384
#define ROW_LEN N_NODES              // 8192
#define BLK     256
#define PER_TH  (ROW_LEN / BLK)      // 32 elements per thread
#define VCHUNKS (PER_TH / 4)         // 8 x float4 per thread
#define CAND_CAP 2048
#define SEL_CAP  64

__device__ __forceinline__ float bits_to_float(uint u) {
    union { uint u; float f; } cv; cv.u = u; return cv.f;
}
__device__ __forceinline__ uint float_to_bits(float f) {
    union { uint u; float f; } cv; cv.f = f; return cv.u;
}
// order-preserving fp32 bits -> uint transform
__device__ __forceinline__ uint sortable32(uint u) {
    return u ^ ((u & 0x80000000u) ? 0xFFFFFFFFu : 0x80000000u);
}
__device__ __forceinline__ uint unsortable32(uint s) {
    return (s & 0x80000000u) ? (s ^ 0x80000000u) : ~s;
}
__device__ __forceinline__ float key_to_val(uint key) {
    return bits_to_float(unsortable32(key));
}

// Defensive decode of the scalar k (int32 / int64 / bf16 / fp32 all -> 32)
__device__ __forceinline__ int decode_k(const void* p) {
    int ki = *(const int*)p;
    if (ki >= 1 && ki <= ROW_LEN) return ki;
    {
        uint b = *(const u16*)p;
        float f = bits_to_float(b << 16);
        int kf = (int)f;
        if (f == (float)kf && kf >= 1 && kf <= ROW_LEN) return kf;
    }
    {
        float g = *(const float*)p;
        int kg = (int)g;
        if (g == (float)kg && kg >= 1 && kg <= ROW_LEN) return kg;
    }
    return 32;
}

// descending bitonic sort of 64 values, one per lane, via shfl_xor.
// final order: lane 0 = max ... lane 63 = min.
__device__ __forceinline__ uint bitonic_desc_u32(uint v, const int lane) {
    #pragma unroll
    for (int size = 2; size <= 64; size <<= 1) {
        #pragma unroll
        for (int stride = size >> 1; stride > 0; stride >>= 1) {
            const uint pv = (uint)__shfl_xor((int)v, stride, 64);
            const bool takeMax = (((lane & stride) != 0) == ((lane & size) != 0));
            v = takeMax ? (v >= pv ? v : pv) : (v <= pv ? v : pv);
        }
    }
    return v;
}

__device__ __forceinline__ u64 bitonic_desc_u64(u64 v, const int lane) {
    #pragma unroll
    for (int size = 2; size <= 64; size <<= 1) {
        #pragma unroll
        for (int stride = size >> 1; stride > 0; stride >>= 1) {
            const u64 pv = __shfl_xor(v, stride, 64);
            const bool takeMax = (((lane & stride) != 0) == ((lane & size) != 0));
            v = takeMax ? (v >= pv ? v : pv) : (v <= pv ? v : pv);
        }
    }
    return v;
}

// -------- kernel 1: h = x @ W^T (fp32), LDS-tiled, coalesced, conflict-free --------
// block computes a 32-row x 64-col tile; K staged in chunks of 128.
// thread (r = tid&15, cb = tid>>4) computes rows {r, r+16}, cols {cb,cb+16,cb+32,cb+48}.
// Within a wave: W reads hit 4 distinct rows (16-lane broadcast each, 4 distinct bank
// groups -> conflict-free); x reads hit 16 rows at stride 132 -> 2-way (free).
#define HM    32
#define HK    128
#define XS_LD 132

__global__ __launch_bounds__(256) void h_kernel(
    const float* __restrict__ x, const float* __restrict__ W, float* __restrict__ hbuf)
{
    __shared__ float x_s[HM * XS_LD];      // 16.9 KB
    __shared__ float w_s[OUT_F * XS_LD];   // 33.8 KB
    const int tid = threadIdx.x;
    const int n0  = blockIdx.x * HM;
    const int r   = tid & 15;
    const int cb  = tid >> 4;              // 0..15

    float a00 = 0.f, a01 = 0.f, a02 = 0.f, a03 = 0.f;
    float a10 = 0.f, a11 = 0.f, a12 = 0.f, a13 = 0.f;

    for (int c = 0; c < IN_F; c += HK) {
        // stage x chunk: 32 rows x 128 cols = 1024 float4, 4 per thread
        #pragma unroll
        for (int j = 0; j < 4; ++j) {
            const int id  = tid + 256 * j;
            const int row = id >> 5;
            const int c4  = id & 31;
            float4 v = *reinterpret_cast<const float4*>(x + (size_t)(n0 + row) * IN_F + c + 4 * c4);
            *reinterpret_cast<float4*>(&x_s[row * XS_LD + 4 * c4]) = v;
        }
        // stage W chunk: 64 rows x 128 cols = 2048 float4, 8 per thread
        #pragma unroll
        for (int j = 0; j < 8; ++j) {
            const int id  = tid + 256 * j;
            const int row = id >> 5;
            const int c4  = id & 31;
            float4 v = *reinterpret_cast<const float4*>(W + (size_t)row * IN_F + c + 4 * c4);
            *reinterpret_cast<float4*>(&w_s[row * XS_LD + 4 * c4]) = v;
        }
        __syncthreads();

        #pragma unroll 2
        for (int k4 = 0; k4 < HK / 4; ++k4) {
            const float4 x0 = *reinterpret_cast<const float4*>(&x_s[r * XS_LD + 4 * k4]);
            const float4 x1 = *reinterpret_cast<const float4*>(&x_s[(r + 16) * XS_LD + 4 * k4]);
            const float4 w0 = *reinterpret_cast<const float4*>(&w_s[(cb +  0) * XS_LD + 4 * k4]);
            const float4 w1 = *reinterpret_cast<const float4*>(&w_s[(cb + 16) * XS_LD + 4 * k4]);
            const float4 w2 = *reinterpret_cast<const float4*>(&w_s[(cb + 32) * XS_LD + 4 * k4]);
            const float4 w3 = *reinterpret_cast<const float4*>(&w_s[(cb + 48) * XS_LD + 4 * k4]);
            a00 = fmaf(x0.x, w0.x, a00); a00 = fmaf(x0.y, w0.y, a00); a00 = fmaf(x0.z, w0.z, a00); a00 = fmaf(x0.w, w0.w, a00);
            a01 = fmaf(x0.x, w1.x, a01); a01 = fmaf(x0.y, w1.y, a01); a01 = fmaf(x0.z, w1.z, a01); a01 = fmaf(x0.w, w1.w, a01);
            a02 = fmaf(x0.x, w2.x, a02); a02 = fmaf(x0.y, w2.y, a02); a02 = fmaf(x0.z, w2.z, a02); a02 = fmaf(x0.w, w2.w, a02);
            a03 = fmaf(x0.x, w3.x, a03); a03 = fmaf(x0.y, w3.y, a03); a03 = fmaf(x0.z, w3.z, a03); a03 = fmaf(x0.w, w3.w, a03);
            a10 = fmaf(x1.x, w0.x, a10); a10 = fmaf(x1.y, w0.y, a10); a10 = fmaf(x1.z, w0.z, a10); a10 = fmaf(x1.w, w0.w, a10);
            a11 = fmaf(x1.x, w1.x, a11); a11 = fmaf(x1.y, w1.y, a11); a11 = fmaf(x1.z, w1.z, a11); a11 = fmaf(x1.w, w1.w, a11);
            a12 = fmaf(x1.x, w2.x, a12); a12 = fmaf(x1.y, w2.y, a12); a12 = fmaf(x1.z, w2.z, a12); a12 = fmaf(x1.w, w2.w, a12);
            a13 = fmaf(x1.x, w3.x, a13); a13 = fmaf(x1.y, w3.y, a13); a13 = fmaf(x1.z, w3.z, a13); a13 = fmaf(x1.w, w3.w, a13);
        }
        __syncthreads();
    }

    float* o0 = hbuf + (size_t)(n0 + r) * OUT_F + cb;
    float* o1 = hbuf + (size_t)(n0 + r + 16) * OUT_F + cb;
    o0[0] = a00; o0[16] = a01; o0[32] = a02; o0[48] = a03;
    o1[0] = a10; o1[16] = a11; o1[32] = a12; o1[48] = a13;
}

// -------- kernel 2: per-row exact top-k + softmax + spmm + dense att write --------
__global__ __launch_bounds__(BLK) void topk_kernel(
    const float* __restrict__ attn,
    const float* __restrict__ hbuf,
    const void* __restrict__ kptr,
    float* __restrict__ outp,      // [N][C*OUT_F]
    float* __restrict__ att_out)   // [ROWS][ROW_LEN]
{
    __shared__ uint  s_lmax[BLK];
    __shared__ uint  s_ck[CAND_CAP];     // candidate sortable keys
    __shared__ u16   s_cidx[CAND_CAP];   // candidate indices
    __shared__ int   s_sel_idx[SEL_CAP];
    __shared__ float s_sel_w[SEL_CAP];
    __shared__ float s_lsum[4];
    __shared__ uint  s_bc[4];            // [0]=pivot p, [1]=max key, [2]=V32, [3]=Tlow
    __shared__ int   s_cnt[2];
    __shared__ float s_l;
    __shared__ int   s_scnt;

    const int tid = threadIdx.x;
    const int row = blockIdx.x;
    int k = decode_k(kptr);              // 32
    if (k > SEL_CAP) k = SEL_CAP;

    if (tid == 0) { s_cnt[0] = 0; s_cnt[1] = 0; }

    const float* rowp = attn    + (size_t)row * ROW_LEN;
    float*       orow = att_out + (size_t)row * ROW_LEN;

    // phase 0: load row (fp32, non-temporal: zero reuse, protect L2 for hbuf)
    // into registers as sortable keys; per-thread max
    uint lk[PER_TH];
    uint lmax = 0;
    #pragma unroll
    for (int c = 0; c < VCHUNKS; ++c) {
        const int vi = c * BLK + tid;
        v4f v = __builtin_nontemporal_load(reinterpret_cast<const v4f*>(rowp) + vi);
        const uint k0 = sortable32(float_to_bits(v[0]));
        const uint k1 = sortable32(float_to_bits(v[1]));
        const uint k2 = sortable32(float_to_bits(v[2]));
        const uint k3 = sortable32(float_to_bits(v[3]));
        lk[c * 4 + 0] = k0; lk[c * 4 + 1] = k1;
        lk[c * 4 + 2] = k2; lk[c * 4 + 3] = k3;
        lmax = max(max(max(lmax, k0), max(k1, k2)), k3);
    }
    s_lmax[tid] = lmax;
    __syncthreads();                                           // A

    // phase 1: wave 0 sorts the 64 combined (max-of-4) maxima -> pivot + row max.
    // No stores are outstanding here, so barrier B has no vmcnt drain stall.
    if (tid < 64) {
        uint cmb = max(max(s_lmax[tid], s_lmax[tid + 64]),
                       max(s_lmax[tid + 128], s_lmax[tid + 192]));
        cmb = bitonic_desc_u32(cmb, tid);
        const uint pk = (uint)__shfl((int)cmb, k - 1, 64);     // k-th largest group max
        if (tid == 0) { s_bc[0] = pk; s_bc[1] = cmb; }         // lane0 = global max
    }
    __syncthreads();                                           // B
    const uint  p = s_bc[0];
    const float m = key_to_val(s_bc[1]);                       // row max value

    // phase 2: compact candidates (keys >= p); expected ~44
    #pragma unroll
    for (int e = 0; e < PER_TH; ++e) {
        if (lk[e] >= p) {
            int pos = atomicAdd(&s_cnt[0], 1);
            if (pos < CAND_CAP) {
                const int c = e >> 2, j = e & 3;
                s_ck[pos]   = lk[e];
                s_cidx[pos] = (u16)((c * BLK + tid) * 4 + j);
            }
        }
    }
    __syncthreads();                                           // C

    int cnt = s_cnt[0];
    if (cnt > CAND_CAP) cnt = CAND_CAP;
    const bool fast = (cnt <= 64);                             // block-uniform

    if (fast) {
        // phase 3 fast: one bitonic sort gives exact top-k with lax.top_k
        // tie-break (value desc, index asc), weights, and the denominator.
        if (tid < 64) {
            u64 v = 0ull;
            if (tid < cnt)
                v = ((u64)s_ck[tid] << 13) | (u64)(0x1FFFu ^ (uint)s_cidx[tid]);
            v = bitonic_desc_u64(v, tid);
            const uint key = (uint)(v >> 13);
            const int  idx = (int)(0x1FFFu ^ (uint)(v & 0x1FFFull));
            const float w  = (tid < k) ? __expf(key_to_val(key) - m) : 0.f;
            float lsum = w;
            #pragma unroll
            for (int off = 1; off < 64; off <<= 1) lsum += __shfl_xor(lsum, off, 64);
            if (tid < k) { s_sel_idx[tid] = idx; s_sel_w[tid] = w; }
            if (tid == 0) { s_l = lsum; s_scnt = k; }
        }
        __syncthreads();                                       // D
    } else {
        // fallback (P(cnt>64) ~ 1e-7/row): exact binary-search selection
        if (tid < 64) {
            // V32 = largest V with count(key >= V) >= k
            uint lo = p, hi = 0xFFFFFFFFu;
            while (lo < hi) {
                const uint d = hi - lo;
                const uint mid = lo + (d >> 1) + (d & 1u);
                int c = 0;
                for (int j = tid; j < cnt; j += 64) c += (s_ck[j] >= mid) ? 1 : 0;
                #pragma unroll
                for (int off = 1; off < 64; off <<= 1) c += __shfl_xor(c, off, 64);
                if (c >= k) lo = mid; else hi = mid - 1;
            }
            const uint V32 = lo;
            int g = 0;
            for (int j = tid; j < cnt; j += 64) g += (s_ck[j] > V32) ? 1 : 0;
            #pragma unroll
            for (int off = 1; off < 64; off <<= 1) g += __shfl_xor(g, off, 64);
            const int e_need = k - g;
            uint tlo = 0u, thi = 0x1FFFu;
            while (tlo < thi) {
                const uint d = thi - tlo;
                const uint mid = tlo + (d >> 1) + (d & 1u);
                int c = 0;
                for (int j = tid; j < cnt; j += 64)
                    c += (s_ck[j] == V32 && (0x1FFFu ^ (uint)s_cidx[j]) >= mid) ? 1 : 0;
                #pragma unroll
                for (int off = 1; off < 64; off <<= 1) c += __shfl_xor(c, off, 64);
                if (c >= e_need) tlo = mid; else thi = mid - 1;
            }
            if (tid == 0) { s_bc[2] = V32; s_bc[3] = tlo; }
        }
        __syncthreads();                                       // D
        const uint V32  = s_bc[2];
        const uint Tlow = s_bc[3];
        float lsum = 0.f;
        #pragma unroll
        for (int e = 0; e < PER_TH; ++e) {
            const int idx = ((e >> 2) * BLK + tid) * 4 + (e & 3);
            const bool sel = (lk[e] > V32) || (lk[e] == V32 && (0x1FFFu ^ (uint)idx) >= Tlow);
            if (sel) {
                const float w = __expf(key_to_val(lk[e]) - m);
                lsum += w;
                int pos = atomicAdd(&s_cnt[1], 1);
                if (pos < SEL_CAP) { s_sel_idx[pos] = idx; s_sel_w[pos] = w; }
            }
        }
        #pragma unroll
        for (int off = 1; off < 64; off <<= 1) lsum += __shfl_xor(lsum, off, 64);
        if ((tid & 63) == 0) s_lsum[tid >> 6] = lsum;
        __syncthreads();                                       // E
        if (tid == 0) {
            s_l = s_lsum[0] + s_lsum[1] + s_lsum[2] + s_lsum[3];
            int sc = s_cnt[1]; if (sc > SEL_CAP) sc = SEL_CAP;
            s_scnt = sc;
        }
        __syncthreads();                                       // F
    }

    const float l     = s_l;
    const float inv_l = (l > 0.f) ? (1.0f / l) : 0.f;
    const int   scnt  = s_scnt;

    // tail phase (concurrent): wave 0 gathers h_prime; waves 1-3 zero-fill the
    // dense att row with non-temporal stores. The store drain lands at the final
    // barrier, overlapped with wave 0's gather latency and other resident blocks.
    const int n  = row & (N_NODES - 1);
    const int ch = row >> 13;
    if (tid < OUT_F) {
        float acc = 0.f;
        for (int j = 0; j < scnt; ++j)
            acc += s_sel_w[j] * hbuf[(size_t)s_sel_idx[j] * OUT_F + tid];
        outp[(size_t)n * (CHEADS * OUT_F) + ch * OUT_F + tid] = acc * inv_l;
    } else {
        const int t = tid - 64;                                // 0..191
        v4f z = {0.f, 0.f, 0.f, 0.f};
        for (int i = t; i < ROW_LEN / 4; i += 192)
            __builtin_nontemporal_store(z, reinterpret_cast<v4f*>(orow) + i);
    }
    __syncthreads();   // drains all zero-fill stores (vmcnt 0) -> scatter is WAW-safe

    // scatter normalized weights over the zeroed att row
    if (tid < scnt)
        orow[s_sel_idx[tid]] = s_sel_w[tid] * inv_l;
}

extern "C" void kernel_launch(void* const* d_in, const int* in_sizes, int n_in,
                              void* d_out, int out_size, void* d_ws, size_t ws_size,
                              hipStream_t stream) {
    const float* x    = (const float*)d_in[0];
    const float* W    = (const float*)d_in[1];
    const float* attn = (const float*)d_in[2];
    const void*  kptr = (const void*)d_in[3];

    float* hbuf = (float*)d_ws;                                   // 8192*64 fp32 = 2 MB
    float* outp = (float*)d_out;                                  // [8192][128]
    float* att_out = outp + (size_t)N_NODES * (CHEADS * OUT_F);   // [16384][8192]

    hipLaunchKernelGGL(h_kernel,    dim3(N_NODES / HM), dim3(BLK), 0, stream, x, W, hbuf);
    hipLaunchKernelGGL(topk_kernel, dim3(ROWS),         dim3(BLK), 0, stream, attn, hbuf, kptr, outp, att_out);
}